// Round 9
// baseline (693.205 us; speedup 1.0000x reference)
//
#include <hip/hip_runtime.h>
#include <stdint.h>

#define B_ 8
#define L_ 1024
#define H_ 768
#define E_ 16
#define W_ 504
#define DFF_ 512
#define N_ 5982
#define NE_ (N_*E_)    // 95712 candidates per batch
#define BNE_ (B_*NE_)  // 765696
#define MAXC_ 6144

typedef unsigned long long u64;
typedef unsigned int u32;

__device__ __forceinline__ int rowstart_of(int s){
    int s0 = W_ - 11; // 493
    if (s <= s0) return 12*s;
    int t = s - s0;
    return 12*s0 + t*11 - (t*(t-1))/2;
}

// ---------------- front: span tables (blocks 0..7) + entity positions (blocks 8..15) ----------------
__global__ void k_front(const int* __restrict__ ent_mask, int* __restrict__ starts,
                        int* __restrict__ ends, int* __restrict__ ent_pos){
    int blk = blockIdx.x; int lane = threadIdx.x;   // 64 threads
    if (blk < 8){
        int s = blk*64 + lane;
        if (s < W_){
            int rs = rowstart_of(s);
            int cnt = min(12, W_ - s);
            for (int i = 0; i < cnt; i++){ starts[rs+i] = s; ends[rs+i] = s+i; }
        }
    } else {
        int b = blk - 8;
        int cnt = 0;
        for (int base = 0; base < L_ && cnt < E_; base += 64){
            int m = ent_mask[b*L_ + base + lane];
            u64 bal = __ballot(m == 1);
            if (m == 1){
                int p = cnt + (int)__popcll(bal & ((1ull<<lane) - 1ull));
                if (p < E_) ent_pos[b*E_ + p] = base + lane;
            }
            cnt += (int)__popcll(bal);
        }
        if (cnt < E_){
            int cnt2 = 0;
            for (int base = 0; base < L_ && cnt + cnt2 < E_; base += 64){
                int m = ent_mask[b*L_ + base + lane];
                u64 bal = __ballot(m != 1);
                if (m != 1){
                    int p = cnt + cnt2 + (int)__popcll(bal & ((1ull<<lane) - 1ull));
                    if (p < E_) ent_pos[b*E_ + p] = base + lane;
                }
                cnt2 += (int)__popcll(bal);
            }
        }
    }
}

// ---------------- token lists: parallel build + deterministic per-word sort ----------------
__global__ void k_toklist(const int* __restrict__ tm, const int* __restrict__ wi,
                          int* __restrict__ tok, int* __restrict__ tokc){
    int i = blockIdx.x*256 + threadIdx.x;
    if (i >= B_*L_) return;
    int w = wi[i];
    if (tm[i] == 1 && w >= 0 && w < W_){
        int b = i / L_;
        int bw = b*W_ + w;
        int pos = atomicAdd(&tokc[bw], 1);
        if (pos < 4) tok[bw*4 + pos] = i - b*L_;
    }
}

__global__ void k_toksort(int* __restrict__ tok, const int* __restrict__ tokc){
    int bw = blockIdx.x*256 + threadIdx.x;
    if (bw >= B_*W_) return;
    int c = min(tokc[bw], 4);
    int v[4];
    for (int k = 0; k < c; k++) v[k] = tok[bw*4 + k];
    for (int a = 1; a < c; a++){ int x = v[a]; int j = a-1; while (j >= 0 && v[j] > x){ v[j+1] = v[j]; j--; } v[j+1] = x; }
    for (int k = 0; k < c; k++) tok[bw*4 + k] = v[k];
}

// ---------------- word mean pooling (gather, deterministic) ----------------
__global__ void k_pool(const float* __restrict__ hs,
                       const int* __restrict__ tok, const int* __restrict__ tokc,
                       float* __restrict__ wemb){
    int idx = blockIdx.x*256 + threadIdx.x;
    if (idx >= B_*W_*H_) return;
    int h = idx % H_; int bw = idx / H_; int b = bw / W_;
    int c = tokc[bw]; int cc = min(c, 4);
    double s = 0.0;
    for (int k = 0; k < cc; k++){
        int l = tok[bw*4 + k];
        s += (double)hs[((size_t)(b*L_ + l))*H_ + h];
    }
    float denom = (float)max(c, 1);
    wemb[idx] = (float)(s / (double)denom);
}

// ---------------- entity MLP layer 1 ----------------
__global__ void k_ent1(const float* __restrict__ hs, const int* __restrict__ ent_pos,
                       const float* __restrict__ w1, const float* __restrict__ b1,
                       float* __restrict__ hidg){
    __shared__ float x[H_];
    int blk = blockIdx.x;            // 256 blocks: be*2 + half
    int be = blk >> 1; int half = blk & 1;
    int b = be >> 4;
    int tid = threadIdx.x;
    int pos = ent_pos[be];
    const float* xp = hs + ((size_t)b*L_ + pos)*H_;
    for (int j = tid; j < H_; j += 256) x[j] = xp[j];
    __syncthreads();
    int d = half*256 + tid;
    float a0=0.f,a1=0.f,a2=0.f,a3=0.f;
    const float* wp = w1 + d;
    #pragma unroll 4
    for (int h = 0; h < H_; h += 4){
        a0 += x[h+0]*wp[(size_t)(h+0)*DFF_];
        a1 += x[h+1]*wp[(size_t)(h+1)*DFF_];
        a2 += x[h+2]*wp[(size_t)(h+2)*DFF_];
        a3 += x[h+3]*wp[(size_t)(h+3)*DFF_];
    }
    float acc = ((a0+a1)+(a2+a3)) + b1[d];
    hidg[(size_t)be*DFF_ + d] = acc > 0.f ? acc : 0.01f*acc;
}

// ---------------- entity MLP layer 2 ----------------
__global__ void k_ent2(const float* __restrict__ hidg,
                       const float* __restrict__ w2, const float* __restrict__ b2,
                       float* __restrict__ ent_vec){
    __shared__ float hsd[DFF_];
    int blk = blockIdx.x;            // 384 blocks: be*3 + third
    int be = blk / 3; int third = blk % 3;
    int tid = threadIdx.x;
    const float* hp = hidg + (size_t)be*DFF_;
    for (int j = tid; j < DFF_; j += 256) hsd[j] = hp[j];
    __syncthreads();
    int j = third*256 + tid;
    float a0=0.f,a1=0.f,a2=0.f,a3=0.f;
    const float* wp = w2 + j;
    #pragma unroll 4
    for (int d = 0; d < DFF_; d += 4){
        a0 += hsd[d+0]*wp[(size_t)(d+0)*H_];
        a1 += hsd[d+1]*wp[(size_t)(d+1)*H_];
        a2 += hsd[d+2]*wp[(size_t)(d+2)*H_];
        a3 += hsd[d+3]*wp[(size_t)(d+3)*H_];
    }
    ent_vec[(size_t)be*H_ + j] = ((a0+a1)+(a2+a3)) + b2[j];
}

// ---------------- M[b] = span_w2 @ ent_vec[b]^T (fp64) + cvec (fused) ----------------
__global__ void k_Mc(const float* __restrict__ span_w2, const float* __restrict__ span_b2,
                     const float* __restrict__ ent_vec, float* __restrict__ M,
                     float* __restrict__ cvec){
    int blk = blockIdx.x;
    int tid = threadIdx.x;
    if (blk < 256){
        int b = blk/32; int dbase = (blk%32)*16;
        int d = dbase + (tid>>4); int e = tid&15;
        const float* ev = ent_vec + ((size_t)b*E_ + e)*H_;
        const float* wr = span_w2 + (size_t)d*H_;
        double p0=0.0, p1=0.0;
        for (int h = 0; h < H_; h += 2){
            p0 += (double)wr[h]*(double)ev[h];
            p1 += (double)wr[h+1]*(double)ev[h+1];
        }
        M[((size_t)b*DFF_ + d)*E_ + e] = (float)(p0+p1);
    } else {
        if (tid < B_*E_){
            const float* ev = ent_vec + (size_t)tid*H_;
            double acc = 0.0;
            for (int h = 0; h < H_; h++) acc += (double)span_b2[h]*(double)ev[h];
            cvec[tid] = (float)acc;
        }
    }
}

// ---------------- P/Q projection: tiled fp32 GEMM, all 8 batches, 64x64 tiles ----------------
__global__ void k_pq(const float* __restrict__ wemb, const float* __restrict__ w1,
                     float* __restrict__ PQ){
    __shared__ float As[16][68];
    __shared__ float Bs[16][68];
    int bx = blockIdx.x & 15;      // col tile
    int by = blockIdx.x >> 4;      // row tile 0..62 (4032 rows exact)
    int tid = threadIdx.x;
    int tm = tid >> 4, tn = tid & 15;
    int colbase = bx*64;
    const float* Bbase = (colbase < DFF_) ? w1 : (w1 + (size_t)H_*DFF_);
    int bcol0 = (colbase < DFF_) ? colbase : (colbase - DFF_);
    float acc[4][4] = {{0.f}};
    int ar = tid >> 2, akq = tid & 3;
    int bkk = tid >> 4, bcq = tid & 15;
    for (int k0 = 0; k0 < H_; k0 += 16){
        {
            int gr = by*64 + ar;
            float4 av = *(const float4*)(wemb + (size_t)gr*H_ + k0 + akq*4);
            As[akq*4+0][ar] = av.x; As[akq*4+1][ar] = av.y;
            As[akq*4+2][ar] = av.z; As[akq*4+3][ar] = av.w;
        }
        {
            float4 bv = *(const float4*)(Bbase + (size_t)(k0+bkk)*DFF_ + bcol0 + bcq*4);
            Bs[bkk][bcq*4+0] = bv.x; Bs[bkk][bcq*4+1] = bv.y;
            Bs[bkk][bcq*4+2] = bv.z; Bs[bkk][bcq*4+3] = bv.w;
        }
        __syncthreads();
        #pragma unroll
        for (int kk = 0; kk < 16; kk++){
            float4 a = *(const float4*)&As[kk][tm*4];
            float4 bv = *(const float4*)&Bs[kk][tn*4];
            acc[0][0] += a.x*bv.x; acc[0][1] += a.x*bv.y; acc[0][2] += a.x*bv.z; acc[0][3] += a.x*bv.w;
            acc[1][0] += a.y*bv.x; acc[1][1] += a.y*bv.y; acc[1][2] += a.y*bv.z; acc[1][3] += a.y*bv.w;
            acc[2][0] += a.z*bv.x; acc[2][1] += a.z*bv.y; acc[2][2] += a.z*bv.z; acc[2][3] += a.z*bv.w;
            acc[3][0] += a.w*bv.x; acc[3][1] += a.w*bv.y; acc[3][2] += a.w*bv.z; acc[3][3] += a.w*bv.w;
        }
        __syncthreads();
    }
    #pragma unroll
    for (int r = 0; r < 4; r++){
        int gr = by*64 + tm*4 + r;
        float4 ov = make_float4(acc[r][0], acc[r][1], acc[r][2], acc[r][3]);
        *(float4*)(PQ + (size_t)gr*1024 + colbase + tn*4) = ov;
    }
}

// ---------------- logits: one block per (b, start s); also zeroes selected region ----------------
__global__ void k_logits(const float* __restrict__ PQ, const float* __restrict__ Mmat,
                         const float* __restrict__ cvec, const float* __restrict__ span_b1,
                         float* __restrict__ logits, float* __restrict__ outL){
    __shared__ float Msh[DFF_*E_];
    __shared__ float Ps[DFF_];
    __shared__ float hid[DFF_];
    __shared__ double red[256];
    __shared__ float csh[E_];
    int blk = blockIdx.x;            // B_*W_ blocks
    int b = blk / W_; int s = blk - b*W_;
    int tid = threadIdx.x;
    for (int i = tid; i < DFF_*E_; i += 256) Msh[i] = Mmat[(size_t)b*DFF_*E_ + i];
    const float* P = PQ + ((size_t)(b*W_ + s))*1024;
    for (int d = tid; d < DFF_; d += 256) Ps[d] = P[d] + span_b1[d];
    if (tid < E_) csh[tid] = cvec[b*E_ + tid];
    __syncthreads();
    int nsp = min(12, W_ - s);
    int nbase = rowstart_of(s);
    for (int i = 0; i < nsp; i++){
        int e = s + i;
        const float* Q = PQ + ((size_t)(b*W_ + e))*1024 + DFF_;
        for (int d = tid; d < DFF_; d += 256){
            float h = Ps[d] + Q[d];
            hid[d] = h > 0.f ? h : 0.01f*h;
        }
        __syncthreads();
        {
            int ee = tid & 15; int g = tid >> 4;
            double a0 = 0.0, a1 = 0.0;
            int d0 = g*32;
            for (int d = d0; d < d0+32; d += 2){
                a0 += (double)hid[d]*(double)Msh[d*E_ + ee];
                a1 += (double)hid[d+1]*(double)Msh[(d+1)*E_ + ee];
            }
            red[tid] = a0 + a1;
        }
        __syncthreads();
        if (tid < E_){
            double t = 0.0;
            for (int g = 0; g < 16; g++) t += red[g*16 + tid];
            float lg = (float)(t + (double)csh[tid]);
            size_t oi = ((size_t)b*N_ + nbase + i)*E_ + tid;
            logits[oi] = lg;
            outL[oi] = lg;
            outL[(size_t)BNE_ + oi] = 0.0f;   // zero the selected region (full coverage, once each)
        }
        __syncthreads();
    }
}

// ---------------- tail: spanbest+compact -> 6-pass radix -> register-coverage decode ----------------
__global__ __launch_bounds__(256) void k_tail(const float* __restrict__ logits,
        const int* __restrict__ starts, const int* __restrict__ ends,
        u64* __restrict__ candA, u64* __restrict__ candB, float* __restrict__ outSel){
    __shared__ u32 hist[16*256];   // 16 KB
    __shared__ u32 wt[4], wpre[5], wtot[4], woff[4];
    __shared__ u32 sbase;
    int b = blockIdx.x; int tid = threadIdx.x;
    int lane = tid & 63, wave = tid >> 6;
    u64* buf0 = candA + (size_t)b*MAXC_;
    u64* buf1 = candB + (size_t)b*MAXC_;
    if (tid == 0) sbase = 0;
    __syncthreads();
    // ---- phase A: per-span best candidate + stable ordered compaction ----
    for (int base = 0; base < N_; base += 256){
        int n = base + tid;
        u64 pk = ~0ull;
        if (n < N_){
            int s = starts[n]; int lenm1 = ends[n] - s;
            const float* lg = logits + (size_t)b*NE_ + (size_t)n*16;
            for (int e = 0; e < 16; e++){
                float prob = 1.0f/(1.0f + expf(-lg[e]));
                if (prob > 0.5f){
                    u32 key24 = (~__float_as_uint(prob)) & 0xFFFFFFu;  // prob in (0.5,1]: top byte constant
                    u64 cand = ((u64)key24 << 24) | ((u64)(u32)s << 8) | ((u64)(u32)lenm1 << 4) | (u64)(u32)e;
                    pk = pk < cand ? pk : cand;   // min = highest prob, tie -> lowest e
                }
            }
        }
        bool f = (pk != ~0ull);
        u64 bal = __ballot(f);
        if (lane == 0) wt[wave] = (u32)__popcll(bal);
        __syncthreads();
        if (tid == 0){ u32 r = 0; for (int w = 0; w < 4; w++){ wpre[w] = r; r += wt[w]; } wpre[4] = r; }
        __syncthreads();
        if (f){
            u32 rank = (u32)__popcll(bal & ((1ull<<lane) - 1ull));
            buf0[sbase + wpre[wave] + rank] = pk;
        }
        __syncthreads();
        if (tid == 0) sbase += wpre[4];
        __syncthreads();
    }
    int n = (int)sbase;
    // ---- phase B: stable LSD radix, 6 x 4-bit over key24 (bits 24..47) ----
    int chunk = (n + 255) >> 8;
    int lo = tid*chunk, hi = lo + chunk; if (hi > n) hi = n; if (lo > n) lo = n;
    for (int p = 0; p < 6; p++){
        u64* ip = (p & 1) ? buf1 : buf0;
        u64* op = (p & 1) ? buf0 : buf1;
        int shift = 24 + 4*p;
        for (int j = tid; j < 16*256; j += 256) hist[j] = 0;
        __syncthreads();
        for (int i = lo; i < hi; i++) hist[((int)((ip[i] >> shift) & 15ull))*256 + tid]++;
        __syncthreads();
        u32 v[16];
        #pragma unroll
        for (int j = 0; j < 16; j++) v[j] = hist[tid*16 + j];
        u32 run = 0;
        #pragma unroll
        for (int j = 0; j < 16; j++){ u32 t2 = v[j]; v[j] = run; run += t2; }
        u32 inc = run;
        for (int d = 1; d < 64; d <<= 1){ u32 o = __shfl_up(inc, d, 64); if (lane >= d) inc += o; }
        u32 excl = inc - run;
        if (lane == 63) wtot[wave] = inc;
        __syncthreads();
        if (tid == 0){ u32 r = 0; for (int w = 0; w < 4; w++){ woff[w] = r; r += wtot[w]; } }
        __syncthreads();
        u32 gbase = woff[wave] + excl;
        #pragma unroll
        for (int j = 0; j < 16; j++) hist[tid*16 + j] = gbase + v[j];
        __syncthreads();
        for (int i = lo; i < hi; i++){
            u64 val = ip[i];
            int d = (int)((val >> shift) & 15ull);
            u32 pz = hist[d*256 + tid];
            hist[d*256 + tid] = pz + 1;
            op[pz] = val;
        }
        __syncthreads();
    }
    __threadfence();
    __syncthreads();
    if (wave != 0) return;
    // ---- phase C: greedy decode, wave 0, coverage in registers (no LDS, no barriers) ----
    u64 c0=0,c1=0,c2=0,c3=0,c4=0,c5=0,c6=0,c7=0;
    int covcnt = 0;
#define COVSEL(w) ((w)==0?c0:(w)==1?c1:(w)==2?c2:(w)==3?c3:(w)==4?c4:(w)==5?c5:(w)==6?c6:c7)
    for (int base = 0; base < n; base += 64){
        int i = base + lane;
        bool has = i < n;
        u64 v = has ? buf0[i] : 0ull;
        u32 lov = (u32)v;
        int ei = lov & 15, lenm1 = (lov>>4) & 15, s = (lov>>8) & 511;
        int len = lenm1 + 1, w0 = s>>6, sh0 = s & 63;
        u64 m0 = has ? (((1ull<<len) - 1ull) << sh0) : 0ull;            // len <= 12
        u64 m1 = (has && sh0+len > 64) ? (((1ull<<len) - 1ull) >> (64-sh0)) : 0ull;
        int w1 = (w0+1 < 8) ? w0+1 : 7;                                 // m1==0 whenever w0==7
        bool tent = has && ((COVSEL(w0) & m0) == 0ull) && ((COVSEL(w1) & m1) == 0ull);
        u64 bal = __ballot(tent);
        bool mytake = false;
        while (bal){
            int j = __builtin_ctzll(bal);
            u32 jlo = (u32)__shfl((int)lov, j);
            int jlenm1 = (jlo>>4) & 15, js = (jlo>>8) & 511;
            int jlen = jlenm1 + 1, jw0 = js>>6, jsh = js & 63;
            u64 jm0 = ((1ull<<jlen) - 1ull) << jsh;
            u64 jm1 = (jsh+jlen > 64) ? (((1ull<<jlen) - 1ull) >> (64-jsh)) : 0ull;
            int jw1 = (jw0+1 < 8) ? jw0+1 : 7;
            covcnt += (int)__popcll(jm0 & ~COVSEL(jw0));
            if (jw1 != jw0) covcnt += (int)__popcll(jm1 & ~COVSEL(jw1));
            c0 |= (jw0==0?jm0:0ull) | (jw1==0?jm1:0ull);
            c1 |= (jw0==1?jm0:0ull) | (jw1==1?jm1:0ull);
            c2 |= (jw0==2?jm0:0ull) | (jw1==2?jm1:0ull);
            c3 |= (jw0==3?jm0:0ull) | (jw1==3?jm1:0ull);
            c4 |= (jw0==4?jm0:0ull) | (jw1==4?jm1:0ull);
            c5 |= (jw0==5?jm0:0ull) | (jw1==5?jm1:0ull);
            c6 |= (jw0==6?jm0:0ull) | (jw1==6?jm1:0ull);
            c7 |= (jw0==7?jm0:0ull) | (jw1==7?jm1:0ull);
            if (lane == j) mytake = true;
            tent = tent && (lane > j) && ((COVSEL(w0) & m0) == 0ull) && ((COVSEL(w1) & m1) == 0ull);
            bal = __ballot(tent);
        }
        if (mytake){
            int nidx = rowstart_of(s) + lenm1;
            outSel[(size_t)b*NE_ + (size_t)(nidx*16 + ei)] = 1.0f;
        }
        if (covcnt >= W_) break;   // coverage full -> all remaining rejected
    }
#undef COVSEL
}

extern "C" void kernel_launch(void* const* d_in, const int* in_sizes, int n_in,
                              void* d_out, int out_size, void* d_ws, size_t ws_size,
                              hipStream_t stream){
    const float* hs        = (const float*)d_in[0];
    const float* ent_w1    = (const float*)d_in[1];
    const float* ent_b1    = (const float*)d_in[2];
    const float* ent_w2    = (const float*)d_in[3];
    const float* ent_b2    = (const float*)d_in[4];
    const float* span_w1   = (const float*)d_in[5];
    const float* span_b1   = (const float*)d_in[6];
    const float* span_w2   = (const float*)d_in[7];
    const float* span_b2   = (const float*)d_in[8];
    const int*  text_mask  = (const int*)d_in[9];
    const int*  ent_mask   = (const int*)d_in[10];
    const int*  word_index = (const int*)d_in[11];
    float* out = (float*)d_out;

    // ---- workspace (~33 MB peak; R1 proved >=45 MB available) ----
    char* wsbase = (char*)d_ws; size_t off = 0;
    auto alloc = [&](size_t bytes)->void*{ void* p = wsbase + off; off = (off + bytes + 255) & ~(size_t)255; return p; };
    char*  region1 = (char*)alloc((size_t)B_*W_*H_*4);    // 12,386,304 B: wemb, later cand bufs
    float* wemb   = (float*)region1;
    u64*   candA  = (u64*)region1;                         // 393,216 B
    u64*   candB  = (u64*)(region1 + (size_t)MAXC_*B_*8);  // +393,216 B
    int*   tok    = (int*)  alloc((size_t)B_*W_*4*4);
    int*   tokc   = (int*)  alloc((size_t)B_*W_*4);
    float* PQ     = (float*)alloc((size_t)B_*W_*1024*4);   // 16,515,072 B (all batches)
    float* logits = (float*)alloc((size_t)BNE_*4);         // 3,062,784 B
    int*   entpos = (int*)  alloc((size_t)B_*E_*4);
    float* hidg   = (float*)alloc((size_t)B_*E_*DFF_*4);
    float* entvec = (float*)alloc((size_t)B_*E_*H_*4);
    float* Mmat   = (float*)alloc((size_t)B_*DFF_*E_*4);
    float* cvec   = (float*)alloc((size_t)B_*E_*4);
    int*   starts = (int*)  alloc((size_t)N_*4);
    int*   ends   = (int*)  alloc((size_t)N_*4);

    hipMemsetAsync(tokc, 0, (size_t)B_*W_*4, stream);

    k_front<<<16,64,0,stream>>>(ent_mask, starts, ends, entpos);
    k_toklist<<<(B_*L_+255)/256,256,0,stream>>>(text_mask, word_index, tok, tokc);
    k_toksort<<<(B_*W_+255)/256,256,0,stream>>>(tok, tokc);
    k_pool<<<(B_*W_*H_+255)/256,256,0,stream>>>(hs, tok, tokc, wemb);
    k_ent1<<<B_*E_*2,256,0,stream>>>(hs, entpos, ent_w1, ent_b1, hidg);
    k_ent2<<<B_*E_*3,256,0,stream>>>(hidg, ent_w2, ent_b2, entvec);
    k_Mc<<<257,256,0,stream>>>(span_w2, span_b2, entvec, Mmat, cvec);
    k_pq<<<63*16,256,0,stream>>>(wemb, span_w1, PQ);
    k_logits<<<B_*W_,256,0,stream>>>(PQ, Mmat, cvec, span_b1, logits, out);
    // wemb dead from here; region1 hosts candA/candB
    k_tail<<<B_,256,0,stream>>>(logits, starts, ends, candA, candB, out + BNE_);
}